// Round 11
// baseline (98.318 us; speedup 1.0000x reference)
//
#include <hip/hip_runtime.h>
#include <stdint.h>

#define BATCH    8
#define NITEMS   1000000
#define NTHR     125000        // NITEMS/8 threads, 8 items each
#define NBLKS    489           // ceil(NTHR/256)
#define NC       64
#define NF       4096
#define NF8      8192          // unified fine space over top-2 coarse bins
#define SBASE    62
#define THRESH   0.96875f      // 62/64, exact in fp32
#define MID63    0.984375f     // 63/64, exact in fp32
#define BUFCAP   512
#define CANDCAP  65536         // clist capacity per batch
#define CANDCAP2 262144        // fallback boundary-bin list capacity
#define CAPC     131072        // cand capacity per batch
#define IMG_W    768.0f
#define IMG_H    432.0f

typedef unsigned long long ull;

static __device__ __forceinline__ float clip0(float v, float hi) {
    return fminf(fmaxf(v, 0.0f), hi);
}
static __device__ __forceinline__ int cbin(float s) {
    int g = (int)(s * (float)NC);                   // pow-2 mul: exact, monotone
    return g > NC - 1 ? NC - 1 : (g < 0 ? 0 : g);
}
static __device__ __forceinline__ int fbin(float s, int g) {
    int f = (int)(s * (float)(NC * NF)) - g * NF;   // pow-2 mul: exact, monotone
    return f > NF - 1 ? NF - 1 : (f < 0 ? 0 : f);
}
static __device__ __forceinline__ unsigned mkbits(float4 box, float s) {
    float x1 = clip0(box.x - box.z * 0.5f, IMG_W);
    float x2 = clip0(box.x + box.z * 0.5f, IMG_W);
    float y1 = clip0(box.y - box.w * 0.5f, IMG_H);
    float y2 = clip0(box.y + box.w * 0.5f, IMG_H);
    bool m = ((x2 - x1) > 16.0f) && ((y2 - y1) > 16.0f);
    return __float_as_uint(m ? s : 0.0f);
}
static __device__ __forceinline__ int g8of(float s) {
    int cb = (s >= MID63) ? 63 : 62;
    return (cb - SBASE) * NF + fbin(s, cb);
}

// ---- K0: zero the tiny per-batch counters (NO hipMemsetAsync — graph-slow) ----
__global__ __launch_bounds__(64)
void k_zero(unsigned* __restrict__ rawCnt, unsigned* __restrict__ ovf) {
    if (threadIdx.x < BATCH) { rawCnt[threadIdx.x] = 0u; ovf[threadIdx.x] = 0u; }
}

// ---- K1: scores stream + ballot-append + inline mask-gather ----
__global__ __launch_bounds__(256)
void k_scores(const float* __restrict__ scores,
              const float4* __restrict__ rps,
              ull* __restrict__ clist,
              unsigned* __restrict__ rawCnt,
              unsigned* __restrict__ ovf) {
    __shared__ ull buf[BUFCAP];
    __shared__ unsigned blkCnt, gBase;
    const int b = blockIdx.y, tid = threadIdx.x;
    const int t = blockIdx.x * 256 + tid;
    const int lane = tid & 63;
    if (tid == 0) blkCnt = 0u;
    __syncthreads();
    const float4* sp4 = (const float4*)(scores + (size_t)b * NITEMS);
    float4 a0 = make_float4(0, 0, 0, 0), a1 = make_float4(0, 0, 0, 0);
    const bool act = (t < NTHR);
    if (act) { a0 = sp4[2 * t]; a1 = sp4[2 * t + 1]; }
    float sv[8] = {a0.x, a0.y, a0.z, a0.w, a1.x, a1.y, a1.z, a1.w};
    const int i0 = t * 8;
    #pragma unroll
    for (int j = 0; j < 8; ++j) {
        bool q = act && (sv[j] >= THRESH);
        ull m = __ballot(q);
        if (m) {
            unsigned pre = (unsigned)__popcll(m & ((1ULL << lane) - 1ULL));
            int leader = __ffsll((long long)m) - 1;
            unsigned bse = 0;
            if (lane == leader) bse = atomicAdd(&blkCnt, (unsigned)__popcll(m));
            bse = (unsigned)__shfl((int)bse, leader);
            if (q) {
                unsigned s2 = bse + pre;
                if (s2 < BUFCAP)
                    buf[s2] = ((ull)__float_as_uint(sv[j]) << 32) |
                              (unsigned)(~(unsigned)(i0 + j));
            }
        }
    }
    __syncthreads();
    unsigned n = blkCnt;
    if (n > BUFCAP) { if (tid == 0) atomicOr(&ovf[b], 1u); n = BUFCAP; }
    if (tid == 0) gBase = atomicAdd(&rawCnt[b], n);
    __syncthreads();
    const unsigned gb = gBase;
    for (unsigned i = tid; i < n; i += 256) {
        unsigned slot = gb + i;
        if (slot >= CANDCAP) break;            // global overflow → K2 falls back
        ull key = buf[i];
        unsigned idx = ~((unsigned)key);
        float4 box = rps[(size_t)b * NITEMS + idx];
        float s = __uint_as_float((unsigned)(key >> 32));
        clist[(size_t)b * CANDCAP + slot] = mkbits(box, s) ? key : 0ull;
    }
}

// ---- K2: per-batch mega-kernel: LDS hist + scan + compact OR full fallback ----
__global__ __launch_bounds__(1024)
void k_mid(const float* __restrict__ scores,
           const float4* __restrict__ rps,
           const ull* __restrict__ clist,
           ull* __restrict__ clist2,
           const unsigned* __restrict__ rawCnt,
           const unsigned* __restrict__ ovf,
           unsigned* __restrict__ fhist8g,
           unsigned* __restrict__ fsuf8g,
           unsigned* __restrict__ csuf64g,
           unsigned* __restrict__ chist64g,
           unsigned* __restrict__ fsufFg,
           unsigned* __restrict__ fhistFg,
           unsigned* __restrict__ meta,
           ull* __restrict__ cand,
           int K) {
    const int b = blockIdx.x, tid = threadIdx.x;
    __shared__ unsigned h[NF8];                 // 32 KB: hist → suffix → slot-ctr
    __shared__ unsigned sc[1024];
    __shared__ unsigned smallA[NC], smallB[NC];
    __shared__ unsigned s_fb8, s_tot, s_cbb, s_nab, s_n2;

    // ---- build 8192-bin histogram in LDS from clist ----
    for (int k = tid; k < NF8; k += 1024) h[k] = 0u;
    __syncthreads();
    const unsigned rawN0 = rawCnt[b];
    unsigned N = rawN0 > CANDCAP ? CANDCAP : rawN0;
    const size_t c0 = (size_t)b * CANDCAP;
    for (unsigned i = tid; i < N; i += 1024) {
        ull key = clist[c0 + i];
        if (!key) continue;
        float s = __uint_as_float((unsigned)(key >> 32));
        atomicAdd(&h[g8of(s)], 1u);
    }
    __syncthreads();
    // ---- suffix scan ----
    unsigned cw[8], pin[8], run = 0;
    #pragma unroll
    for (int k = 0; k < 8; ++k) {
        cw[k] = h[NF8 - 1 - (tid * 8 + k)];
        run += cw[k]; pin[k] = run;
    }
    sc[tid] = run; __syncthreads();
    unsigned x = run;
    for (int off = 1; off < 1024; off <<= 1) {
        unsigned tv = (tid >= off) ? sc[tid - off] : 0u;
        __syncthreads();
        x += tv; sc[tid] = x;
        __syncthreads();
    }
    const unsigned exclBase = x - run;
    const unsigned alive = sc[1023];
    if (tid == 0) { s_fb8 = 0u; s_tot = alive; }
    __syncthreads();
    #pragma unroll
    for (int k = 0; k < 8; ++k) {
        int g = NF8 - 1 - (tid * 8 + k);
        unsigned excl = exclBase + pin[k] - cw[k];
        fsuf8g[b * NF8 + g] = excl;
        fhist8g[b * NF8 + g] = cw[k];
        if (excl < (unsigned)K && excl + cw[k] >= (unsigned)K) {
            s_fb8 = (unsigned)g; s_tot = excl + cw[k];
        }
    }
    __syncthreads();
    #pragma unroll
    for (int k = 0; k < 8; ++k) {               // h := slot-counter bases
        int g = NF8 - 1 - (tid * 8 + k);
        h[g] = exclBase + pin[k] - cw[k];
    }
    __syncthreads();
    const bool fast = (alive >= (unsigned)K) && (ovf[b] == 0u) &&
                      (rawN0 <= (unsigned)CANDCAP) && (s_tot <= (unsigned)CAPC);
    if (tid == 0) {
        meta[b * 8 + 4] = fast ? 1u : 0u;
        meta[b * 8 + 2] = s_fb8;
        meta[b * 8 + 3] = s_tot;
    }
    __syncthreads();
    if (fast) {
        const unsigned fb8v = s_fb8;
        for (unsigned i = tid; i < N; i += 1024) {
            ull key = clist[c0 + i];
            if (!key) continue;
            float s = __uint_as_float((unsigned)(key >> 32));
            int g8 = g8of(s);
            if ((unsigned)g8 < fb8v) continue;
            unsigned slot = atomicAdd(&h[g8], 1u);
            if (slot < CAPC) cand[(size_t)b * CAPC + slot] = key;
        }
        return;
    }
    // ---- generic fallback (block-local, correctness-only) ----
    if (tid < NC) smallA[tid] = 0u;
    __syncthreads();
    const size_t base = (size_t)b * NITEMS;
    for (int i = tid; i < NITEMS; i += 1024) {
        unsigned bits = mkbits(rps[base + i], scores[base + i]);
        if (bits) atomicAdd(&smallA[cbin(__uint_as_float(bits))], 1u);
    }
    __syncthreads();
    if (tid == 0) {
        unsigned runc = 0, cbb = 0, nab = 0; bool found = false;
        for (int g = NC - 1; g >= 0; --g) {
            unsigned c = smallA[g];
            csuf64g[b * NC + g] = runc; chist64g[b * NC + g] = c;
            smallB[g] = runc;
            if (!found && runc < (unsigned)K && runc + c >= (unsigned)K) {
                cbb = (unsigned)g; nab = runc; found = true;
            }
            runc += c;
        }
        s_cbb = cbb; s_nab = nab; s_n2 = 0u;
        meta[b * 8 + 0] = cbb; meta[b * 8 + 1] = nab;
    }
    __syncthreads();
    const unsigned cbb = s_cbb, nab = s_nab;
    if (tid < NC) smallA[tid] = smallB[tid];    // above-bin slot counters
    for (int k = tid; k < NF; k += 1024) h[k] = 0u;
    __syncthreads();
    for (int i = tid; i < NITEMS; i += 1024) {
        unsigned bits = mkbits(rps[base + i], scores[base + i]);
        if (!bits) continue;
        float s = __uint_as_float(bits);
        int g = cbin(s);
        if ((unsigned)g < cbb) continue;
        ull key = ((ull)bits << 32) | (unsigned)(~(unsigned)i);
        if ((unsigned)g > cbb) {
            unsigned slot = atomicAdd(&smallA[g], 1u);
            if (slot < CAPC) cand[(size_t)b * CAPC + slot] = key;
        } else {
            unsigned s2 = atomicAdd(&s_n2, 1u);
            if (s2 < CANDCAP2) clist2[(size_t)b * CANDCAP2 + s2] = key;
            atomicAdd(&h[fbin(s, (int)cbb)], 1u);
        }
    }
    __syncthreads();
    unsigned n2 = s_n2 > CANDCAP2 ? CANDCAP2 : s_n2;
    unsigned fcw[4], fpin[4], frun = 0;
    #pragma unroll
    for (int k = 0; k < 4; ++k) {
        fcw[k] = h[NF - 1 - (tid * 4 + k)];
        frun += fcw[k]; fpin[k] = frun;
    }
    sc[tid] = frun; __syncthreads();
    unsigned fx = frun;
    for (int off = 1; off < 1024; off <<= 1) {
        unsigned tv = (tid >= off) ? sc[tid - off] : 0u;
        __syncthreads();
        fx += tv; sc[tid] = fx;
        __syncthreads();
    }
    const unsigned fexcl = fx - frun;
    const unsigned ftot = sc[1023];
    if (tid == 0) { s_fb8 = 0u; s_tot = nab + ftot; }
    __syncthreads();
    #pragma unroll
    for (int k = 0; k < 4; ++k) {
        int g = NF - 1 - (tid * 4 + k);
        unsigned excl = fexcl + fpin[k] - fcw[k];
        fsufFg[b * NF + g] = excl; fhistFg[b * NF + g] = fcw[k];
        unsigned t0 = nab + excl;
        if (t0 < (unsigned)K && t0 + fcw[k] >= (unsigned)K) {
            s_fb8 = (unsigned)g; s_tot = t0 + fcw[k];
        }
        h[g] = nab + excl;                      // slot counter base
    }
    __syncthreads();
    if (tid == 0) { meta[b * 8 + 2] = s_fb8; meta[b * 8 + 3] = s_tot; }
    __syncthreads();
    const unsigned fbv = s_fb8;
    for (unsigned i = tid; i < n2; i += 1024) {
        ull key = clist2[(size_t)b * CANDCAP2 + i];
        unsigned bits = (unsigned)(key >> 32);
        float s = __uint_as_float(bits);
        int f = fbin(s, (int)cbb);
        if ((unsigned)f < fbv) continue;
        unsigned slot = atomicAdd(&h[f], 1u);
        if (slot < CAPC) cand[(size_t)b * CAPC + slot] = key;
    }
}

// ---- K3: rank within tiny segment, gather, write outputs ----
__global__ __launch_bounds__(256)
void k_rank_out(const ull* __restrict__ cand,
                const unsigned* __restrict__ meta,
                const unsigned* __restrict__ fsuf8g,
                const unsigned* __restrict__ fhist8g,
                const unsigned* __restrict__ csuf64g,
                const unsigned* __restrict__ chist64g,
                const unsigned* __restrict__ fsufFg,
                const unsigned* __restrict__ fhistFg,
                const float4* __restrict__ rps,
                float* __restrict__ out,
                int K) {
    const int b = blockIdx.y;
    unsigned total = meta[b * 8 + 3];
    if (total > CAPC) total = CAPC;
    const unsigned fast = meta[b * 8 + 4];
    for (unsigned p = blockIdx.x * 256 + threadIdx.x; p < total;
         p += gridDim.x * 256) {
        const ull key = cand[(size_t)b * CAPC + p];
        const float s = __uint_as_float((unsigned)(key >> 32));
        unsigned sbase, scnt;
        if (fast) {
            int g8 = g8of(s);
            sbase = fsuf8g[b * NF8 + g8];
            scnt  = fhist8g[b * NF8 + g8];
        } else {
            const unsigned cbb = meta[b * 8 + 0], nab = meta[b * 8 + 1];
            int g = cbin(s);
            if ((unsigned)g > cbb) {
                sbase = csuf64g[b * NC + g];
                scnt  = chist64g[b * NC + g];
            } else {
                int f = fbin(s, (int)g);
                sbase = nab + fsufFg[b * NF + f];
                scnt  = fhistFg[b * NF + f];
            }
        }
        unsigned send = sbase + scnt;
        if (send > total) send = total;
        unsigned rank = sbase;
        for (unsigned j = sbase; j < send; ++j)
            rank += (cand[(size_t)b * CAPC + j] > key) ? 1u : 0u;
        if (rank < (unsigned)K) {
            unsigned idx = ~((unsigned)key);
            if (idx >= (unsigned)NITEMS) idx = 0;
            float4 box = rps[(size_t)b * NITEMS + idx];
            float x1 = clip0(box.x - box.z * 0.5f, IMG_W);
            float x2 = clip0(box.x + box.z * 0.5f, IMG_W);
            float y1 = clip0(box.y - box.w * 0.5f, IMG_H);
            float y2 = clip0(box.y + box.w * 0.5f, IMG_H);
            float nw = x2 - x1, nh = y2 - y1;
            float nx = x1 + nw * 0.5f, ny = y1 + nh * 0.5f;
            ((float4*)out)[(size_t)b * K + rank] = make_float4(nx, ny, nw, nh);
            out[(size_t)BATCH * K * 4 + (size_t)b * K + rank] = s;
        }
    }
}

extern "C" void kernel_launch(void* const* d_in, const int* in_sizes, int n_in,
                              void* d_out, int out_size, void* d_ws, size_t ws_size,
                              hipStream_t stream) {
    const float*  scores = (const float*)d_in[0];
    const float4* rps    = (const float4*)d_in[1];
    const int K = out_size / (BATCH * 5);               // 12000

    // ---- workspace layout (non-overlapping; sizes verified) ----
    uint8_t* w = (uint8_t*)d_ws;
    ull* clist        = (ull*)(w);                      //          0 + 4,194,304
    ull* cand         = (ull*)(w +  4500000);           //  4,500,000 + 8,388,608
    ull* clist2       = (ull*)(w + 13000000);           // 13,000,000 + 16,777,216
    unsigned* fhist8g = (unsigned*)(w + 30000000);      // 30,000,000 + 262,144
    unsigned* rawCnt  = (unsigned*)(w + 30262144);      //         32
    unsigned* ovf     = (unsigned*)(w + 30262176);      //         32
    unsigned* fsuf8g  = (unsigned*)(w + 30400000);      // 30,400,000 + 262,144
    unsigned* meta    = (unsigned*)(w + 30700000);      // 30,700,000 + 256
    unsigned* csuf64g = (unsigned*)(w + 30701000);      // 30,701,000 + 2,048
    unsigned* chist64g= (unsigned*)(w + 30704000);      // 30,704,000 + 2,048
    unsigned* fsufFg  = (unsigned*)(w + 30710000);      // 30,710,000 + 131,072
    unsigned* fhistFg = (unsigned*)(w + 30850000);      // 30,850,000 + 131,072

    k_zero<<<dim3(1), dim3(64), 0, stream>>>(rawCnt, ovf);
    k_scores<<<dim3(NBLKS, BATCH), dim3(256), 0, stream>>>(scores, rps, clist,
                                                           rawCnt, ovf);
    k_mid<<<dim3(BATCH), dim3(1024), 0, stream>>>(scores, rps, clist, clist2,
                                                  rawCnt, ovf, fhist8g, fsuf8g,
                                                  csuf64g, chist64g, fsufFg, fhistFg,
                                                  meta, cand, K);
    k_rank_out<<<dim3(128, BATCH), dim3(256), 0, stream>>>(cand, meta, fsuf8g, fhist8g,
                                                           csuf64g, chist64g, fsufFg,
                                                           fhistFg, rps,
                                                           (float*)d_out, K);
}